// Round 13
// baseline (143.511 us; speedup 1.0000x reference)
//
#include <hip/hip_runtime.h>
#include <cstdint>
#include <cstddef>

#define NB    16
#define NC    512
#define NHW   576
#define NTF   512
#define NHEAD 8
#define NCPH  64
#define ATT_SCALE 0.125f
#define SCALE_L2E 0.18033688011112042f   // 0.125 * log2(e)

typedef float  floatx4 __attribute__((ext_vector_type(4)));
typedef short  short8  __attribute__((ext_vector_type(8)));
typedef unsigned short ushortx4 __attribute__((ext_vector_type(4)));

__device__ __forceinline__ unsigned short f2bf(float f) {
    unsigned int u = __float_as_uint(f);
    u += 0x7fffu + ((u >> 16) & 1u);
    return (unsigned short)(u >> 16);
}
__device__ __forceinline__ float bf2f(unsigned short h) {
    return __uint_as_float(((unsigned int)h) << 16);
}

// ---------------------------------------------------------------- fused prep
// Block ranges:
//   [0, 4096):        weight bf16 conversion (Wq,Wk -> Wqkm rows 0..1023; Wv_bf; Wr_bf)
//   [4096, 4608):     WmT[n][k] = bf16(Wm[k][n]) full 1024 rows
//   [4608, 9216):     xT[b][p][c] = bf16(x[b][c][p])
__global__ void k_prep_all(const float* __restrict__ Wq, const float* __restrict__ Wk,
                           const float* __restrict__ Wv, const float* __restrict__ Wr,
                           const float* __restrict__ Wm, const float* __restrict__ x,
                           unsigned short* __restrict__ Wqkm,
                           unsigned short* __restrict__ Wv_bf,
                           unsigned short* __restrict__ Wr_bf,
                           unsigned short* __restrict__ WmT,
                           unsigned short* __restrict__ xT) {
    __shared__ float tile[32][33];
    int bid = blockIdx.x;
    int tid = threadIdx.x;

    if (bid < 4096) {
        int i = bid * 256 + tid;
        if (i < 1024 * 512) {
            int r = i >> 9, c = i & 511;
            float v = (r < 512) ? Wq[r * 512 + c] : Wk[(r - 512) * 512 + c];
            Wqkm[i] = f2bf(v);
        } else {
            int j = i - 1024 * 512;
            if (j < 512 * 512) Wv_bf[j] = f2bf(Wv[j]);
            else               Wr_bf[j - 512 * 512] = f2bf(Wr[j - 512 * 512]);
        }
        return;
    }

    int tx = tid & 31, ty = tid >> 5;
    if (bid < 4608) {
        int bi = bid - 4096;                  // 0..511
        int n0 = (bi & 31) * 32, k0 = (bi >> 5) * 32;
        #pragma unroll
        for (int k = 0; k < 4; k++)
            tile[ty + k * 8][tx] = Wm[(size_t)(k0 + ty + k * 8) * 1024 + n0 + tx];
        __syncthreads();
        #pragma unroll
        for (int k = 0; k < 4; k++)
            WmT[(size_t)(n0 + ty + k * 8) * 512 + k0 + tx] = f2bf(tile[tx][ty + k * 8]);
        return;
    }

    int bi = bid - 4608;                      // 0..4607
    int pi = bi % 18, rem = bi / 18;
    int ci = rem & 15, b = rem >> 4;
    int p0 = pi * 32, c0 = ci * 32;
    const float* xb = x + (size_t)b * NC * NHW;
    #pragma unroll
    for (int k = 0; k < 4; k++)
        tile[ty + k * 8][tx] = xb[(size_t)(c0 + ty + k * 8) * NHW + p0 + tx];
    __syncthreads();
    unsigned short* xTb = xT + (size_t)b * NHW * NC;
    #pragma unroll
    for (int k = 0; k < 4; k++)
        xTb[(size_t)(p0 + ty + k * 8) * NC + c0 + tx] = f2bf(tile[tx][ty + k * 8]);
}

// tm[b][o] = dot(Wt_w[o], t[b]) + Wt_b[o];  tmerge[b][o] = dot(Wvm_txt[o], t[b])
__global__ void k_prep_t(const float* __restrict__ t, const float* __restrict__ Wt_w,
                         const float* __restrict__ Wt_b, const float* __restrict__ Wvm_txt,
                         float* __restrict__ tm, float* __restrict__ tmerge) {
    __shared__ float ts[512];
    int b = blockIdx.x;
    int tid = threadIdx.x;
    ts[tid]       = t[b * 512 + tid];
    ts[tid + 256] = t[b * 512 + tid + 256];
    __syncthreads();
    int oo = blockIdx.y * 256 + tid;
    const float* Wrow = (oo < 512) ? (Wt_w + (size_t)oo * 512)
                                   : (Wvm_txt + (size_t)(oo - 512) * 512);
    float acc = 0.f;
    #pragma unroll 4
    for (int c = 0; c < 512; c += 4) {
        float4 w = *reinterpret_cast<const float4*>(Wrow + c);
        acc += w.x * ts[c] + w.y * ts[c + 1] + w.z * ts[c + 2] + w.w * ts[c + 3];
    }
    if (oo < 512) tm[b * 512 + oo] = acc + Wt_b[oo];
    else          tmerge[b * 512 + (oo - 512)] = acc;
}

// ---------------------------------------------------------------- 128x128 LDS-staged GEMM core

__device__ __forceinline__ void g128_stage(const unsigned short* __restrict__ src,
                                           unsigned short* lds, int tid) {
    int row  = tid >> 3;
    int slot = (tid & 7) ^ (row & 7);
    #pragma unroll
    for (int i = 0; i < 4; i++) {
        __builtin_amdgcn_global_load_lds(
            (const __attribute__((address_space(1))) unsigned int*)(src + (size_t)(32 * i + row) * NC + slot * 8),
            (__attribute__((address_space(3))) unsigned int*)(lds + i * 2048 + tid * 8), 16, 0, 0);
    }
}

__device__ __forceinline__ void g128_main(const unsigned short* __restrict__ Asrc,
                                          const unsigned short* __restrict__ Bsrc,
                                          unsigned short (*At)[8192], unsigned short (*Bt)[8192],
                                          int tid, int lane, int wr, int wc,
                                          floatx4 (&acc)[4][4]) {
    int cl = lane & 15, hi = lane >> 4, sx = cl & 7;

    g128_stage(Asrc, At[0], tid);
    g128_stage(Bsrc, Bt[0], tid);
    __syncthreads();

    int buf = 0;
    for (int ks = 0; ks < 8; ks++) {
        if (ks < 7) {
            g128_stage(Asrc + (ks + 1) * 64, At[buf ^ 1], tid);
            g128_stage(Bsrc + (ks + 1) * 64, Bt[buf ^ 1], tid);
        }
        #pragma unroll
        for (int kk = 0; kk < 2; kk++) {
            int sl = ((kk << 2) + hi) ^ sx;
            short8 a[4], bb[4];
            #pragma unroll
            for (int i = 0; i < 4; i++)
                a[i] = *reinterpret_cast<const short8*>(&At[buf][(wr * 64 + i * 16 + cl) * 64 + sl * 8]);
            #pragma unroll
            for (int j = 0; j < 4; j++)
                bb[j] = *reinterpret_cast<const short8*>(&Bt[buf][(wc * 64 + j * 16 + cl) * 64 + sl * 8]);
            #pragma unroll
            for (int i = 0; i < 4; i++)
                #pragma unroll
                for (int j = 0; j < 4; j++)
                    acc[i][j] = __builtin_amdgcn_mfma_f32_16x16x32_bf16(a[i], bb[j], acc[i][j], 0, 0, 0);
        }
        __syncthreads();
        buf ^= 1;
    }
}

// Wvm = Wv @ Wm  (via WmT): cols 0..511 -> bf16 Wqkm rows 1024+, cols 512+ -> f32 Wvm_txt.
__global__ void k_fold(const unsigned short* __restrict__ Wv_bf,
                       const unsigned short* __restrict__ WmT,
                       unsigned short* __restrict__ Wqkm,
                       float* __restrict__ Wvm_txt) {
    __shared__ unsigned short At[2][8192], Bt[2][8192];
    int tid = threadIdx.x, lane = tid & 63, wid = tid >> 6;
    int wr = wid >> 1, wc = wid & 1;
    int m = blockIdx.x >> 3, nt = blockIdx.x & 7;
    int o0 = m * 128, n0 = nt * 128;

    floatx4 acc[4][4];
    floatx4 zz = {0.f, 0.f, 0.f, 0.f};
    #pragma unroll
    for (int i = 0; i < 4; i++)
        #pragma unroll
        for (int j = 0; j < 4; j++) acc[i][j] = zz;

    g128_main(Wv_bf + (size_t)o0 * NC, WmT + (size_t)n0 * NC, At, Bt, tid, lane, wr, wc, acc);

    int cl = lane & 15, r0 = (lane >> 4) * 4;
    #pragma unroll
    for (int i = 0; i < 4; i++)
        #pragma unroll
        for (int jn = 0; jn < 4; jn++) {
            int n = n0 + wc * 64 + jn * 16 + cl;
            #pragma unroll
            for (int j = 0; j < 4; j++) {
                int o = o0 + wr * 64 + i * 16 + r0 + j;
                if (n0 < 512) Wqkm[(size_t)(1024 + o) * 512 + n] = f2bf(acc[i][jn][j]);
                else          Wvm_txt[(size_t)o * 512 + (n - 512)] = acc[i][jn][j];
            }
        }
}

// Y = Wstack @ xT^T.  m<8: QT/KT transposed [n][o_local]; m>=8: V natural [b][c][p] + tmerge bias.
__global__ void k_gemm_qkm(const unsigned short* __restrict__ Wqkm,
                           const unsigned short* __restrict__ xT,
                           const float* __restrict__ tmerge,
                           unsigned short* __restrict__ QT,
                           unsigned short* __restrict__ KT,
                           unsigned short* __restrict__ V) {
    __shared__ unsigned short At[2][8192], Bt[2][8192];
    int tid = threadIdx.x, lane = tid & 63, wid = tid >> 6;
    int wr = wid >> 1, wc = wid & 1;
    int bid = blockIdx.x;
    int xcd = bid & 7, slot = bid >> 3;
    int m = slot / 9, nl = slot % 9;
    int n0 = (xcd * 9 + nl) * 128;
    int o0 = m * 128;

    floatx4 acc[4][4];
    floatx4 zz = {0.f, 0.f, 0.f, 0.f};
    #pragma unroll
    for (int i = 0; i < 4; i++)
        #pragma unroll
        for (int j = 0; j < 4; j++) acc[i][j] = zz;

    g128_main(Wqkm + (size_t)o0 * NC, xT + (size_t)n0 * NC, At, Bt, tid, lane, wr, wc, acc);

    int cl = lane & 15, r0 = (lane >> 4) * 4;
    int ob = (m & 3) * 128 + wr * 64;

    if (m < 8) {
        unsigned short* Yt = (m < 4) ? QT : KT;
        #pragma unroll
        for (int i = 0; i < 4; i++) {
            int ol = ob + i * 16 + r0;
            #pragma unroll
            for (int jn = 0; jn < 4; jn++) {
                int n = n0 + wc * 64 + jn * 16 + cl;
                ushortx4 pk;
                pk[0] = f2bf(acc[i][jn][0]);
                pk[1] = f2bf(acc[i][jn][1]);
                pk[2] = f2bf(acc[i][jn][2]);
                pk[3] = f2bf(acc[i][jn][3]);
                *reinterpret_cast<ushortx4*>(Yt + (size_t)n * NC + ol) = pk;
            }
        }
    } else {
        #pragma unroll
        for (int i = 0; i < 4; i++) {
            int ol = ob + i * 16 + r0;
            #pragma unroll
            for (int jn = 0; jn < 4; jn++) {
                int n = n0 + wc * 64 + jn * 16 + cl;
                int b = n / NHW, p = n - b * NHW;
                float4 tv = *reinterpret_cast<const float4*>(tmerge + b * NC + ol);
                float bias[4] = {tv.x, tv.y, tv.z, tv.w};
                #pragma unroll
                for (int j = 0; j < 4; j++)
                    V[((size_t)b * NC + ol + j) * NHW + p] = f2bf(acc[i][jn][j] + bias[j]);
            }
        }
    }
}

// out = Wr @ AO^T + Wr_b -> natural f32 [b][o][p].
__global__ void k_gemm_final(const unsigned short* __restrict__ Wr_bf,
                             const unsigned short* __restrict__ AO,
                             const float* __restrict__ Wr_b,
                             float* __restrict__ out) {
    __shared__ unsigned short At[2][8192], Bt[2][8192];
    int tid = threadIdx.x, lane = tid & 63, wid = tid >> 6;
    int wr = wid >> 1, wc = wid & 1;
    int bid = blockIdx.x;
    int xcd = bid & 7, slot = bid >> 3;
    int m = slot / 9, nl = slot % 9;
    int n0 = (xcd * 9 + nl) * 128;
    int o0 = m * 128;

    floatx4 acc[4][4];
    floatx4 zz = {0.f, 0.f, 0.f, 0.f};
    #pragma unroll
    for (int i = 0; i < 4; i++)
        #pragma unroll
        for (int j = 0; j < 4; j++) acc[i][j] = zz;

    g128_main(Wr_bf + (size_t)o0 * NC, AO + (size_t)n0 * NC, At, Bt, tid, lane, wr, wc, acc);

    int cl = lane & 15, r0 = (lane >> 4) * 4;
    #pragma unroll
    for (int i = 0; i < 4; i++) {
        float4 bv = *reinterpret_cast<const float4*>(Wr_b + o0 + wr * 64 + i * 16 + r0);
        float bias[4] = {bv.x, bv.y, bv.z, bv.w};
        #pragma unroll
        for (int jn = 0; jn < 4; jn++) {
            int n = n0 + wc * 64 + jn * 16 + cl;
            int b = n / NHW, p = n - b * NHW;
            #pragma unroll
            for (int j = 0; j < 4; j++) {
                int c = o0 + wr * 64 + i * 16 + r0 + j;
                out[((size_t)b * NC + c) * NHW + p] = acc[i][jn][j] + bias[j];
            }
        }
    }
}

// ---------------------------------------------------------------- cross + o2

__global__ void k_cross_o2(const unsigned short* __restrict__ xT,
                           const unsigned short* __restrict__ V,
                           const float* __restrict__ tm,
                           float* __restrict__ o2) {
    __shared__ float tms[64];
    __shared__ float ss[576];
    __shared__ float red[8];
    __shared__ float part[4][64];
    int bh = blockIdx.x;
    int b = bh >> 3, h = bh & 7;
    int tid = threadIdx.x;

    if (tid < 64) tms[tid] = tm[b * 512 + h * 64 + tid];
    __syncthreads();

    for (int m = tid; m < 576; m += 256) {
        const short8* xr8 = reinterpret_cast<const short8*>(xT + ((size_t)b * NHW + m) * NC + h * 64);
        float acc = 0.f;
        #pragma unroll
        for (int cc = 0; cc < 8; cc++) {
            short8 v8 = xr8[cc];
            #pragma unroll
            for (int q = 0; q < 8; q++)
                acc += bf2f((unsigned short)v8[q]) * tms[cc * 8 + q];
        }
        ss[m] = acc * ATT_SCALE;
    }
    __syncthreads();

    float pmax = -3e38f;
    for (int m = tid; m < 576; m += 256) pmax = fmaxf(pmax, ss[m]);
    #pragma unroll
    for (int off = 32; off; off >>= 1) pmax = fmaxf(pmax, __shfl_xor(pmax, off));
    if ((tid & 63) == 0) red[tid >> 6] = pmax;
    __syncthreads();
    float mx = fmaxf(fmaxf(red[0], red[1]), fmaxf(red[2], red[3]));

    float psum = 0.f;
    for (int m = tid; m < 576; m += 256) {
        float e = __expf(ss[m] - mx);
        ss[m] = e;
        psum += e;
    }
    #pragma unroll
    for (int off = 32; off; off >>= 1) psum += __shfl_xor(psum, off);
    if ((tid & 63) == 0) red[4 + (tid >> 6)] = psum;
    __syncthreads();
    float inv = 1.f / (red[4] + red[5] + red[6] + red[7]);

    int c = tid & 63, seg = tid >> 6;
    const unsigned short* vr = V + ((size_t)b * NC + h * 64 + c) * NHW;
    float pa = 0.f;
    for (int m = seg * 144; m < seg * 144 + 144; m++) pa += bf2f(vr[m]) * ss[m];
    part[seg][c] = pa;
    __syncthreads();
    if (tid < 64)
        o2[(b * 8 + h) * 64 + tid] =
            (part[0][tid] + part[1][tid] + part[2][tid] + part[3][tid]) * inv;
}

// ---------------------------------------------------------------- attention core
// 4 waves x 16 q-rows, grid 1152, XCD-grouped. K staged via double-buffered
// global_load_lds (XOR-swizzled pair). V read DIRECT from global/L2 (per-XCD V
// working set 1.2 MB L2-fits; 4 waves/block share the same 8 KB V-tile via L1)
// -- drops 16 KB LDS (5 blocks/CU) and halves the per-chunk vmcnt barrier drain.

__global__ void k_attn(const unsigned short* __restrict__ QT,
                       const unsigned short* __restrict__ KT,
                       const unsigned short* __restrict__ V,
                       const float* __restrict__ o2,
                       unsigned short* __restrict__ AO) {
    __shared__ unsigned short Ktile[2][64][64];
    __shared__ unsigned short pbuf[4][16][88];
    int tid  = threadIdx.x;
    int lane = tid & 63, wid = tid >> 6;

    int bid  = blockIdx.x;
    int xcd  = bid & 7;
    int slot = bid >> 3;
    int bh   = xcd * 16 + slot / 9;
    int qt   = slot % 9;
    int b = bh >> 3, h = bh & 7;
    int n0 = qt * 64 + wid * 16;
    int cl = lane & 15;
    int r0 = (lane >> 4) * 4;
    int part = lane >> 4;
    int ko = part * 8;

    const unsigned short* Qb = QT + ((size_t)b * NHW + n0) * NC + h * 64;
    const unsigned short* Kb = KT + (size_t)b * NHW * NC + h * 64;
    const unsigned short* Vb = V  + ((size_t)b * NC + h * 64) * NHW;

    short8 aq0 = *reinterpret_cast<const short8*>(Qb + (size_t)cl * NC + ko);
    short8 aq1 = *reinterpret_cast<const short8*>(Qb + (size_t)cl * NC + 32 + ko);

    int srow = lane >> 3;
    int scol = (lane & 7) ^ srow;

    floatx4 zz = {0.f, 0.f, 0.f, 0.f};
    floatx4 oacc[4] = {zz, zz, zz, zz};
    float es[4] = {0.f, 0.f, 0.f, 0.f};

    {
        const unsigned short* ks = Kb + (size_t)(wid * 16 + srow) * NC + scol * 8;
        #pragma unroll
        for (int i = 0; i < 2; i++) {
            __builtin_amdgcn_global_load_lds(
                (const __attribute__((address_space(1))) unsigned int*)(ks + (size_t)i * 8 * NC),
                (__attribute__((address_space(3))) unsigned int*)&Ktile[0][wid * 16 + i * 8][0], 16, 0, 0);
        }
    }
    __syncthreads();

    int buf = 0;
    for (int chk = 0; chk < 9; chk++) {
        int m0 = chk * 64;
        if (chk < 8) {
            const unsigned short* ks = Kb + (size_t)(m0 + 64 + wid * 16 + srow) * NC + scol * 8;
            #pragma unroll
            for (int i = 0; i < 2; i++) {
                __builtin_amdgcn_global_load_lds(
                    (const __attribute__((address_space(1))) unsigned int*)(ks + (size_t)i * 8 * NC),
                    (__attribute__((address_space(3))) unsigned int*)&Ktile[buf ^ 1][wid * 16 + i * 8][0], 16, 0, 0);
            }
        }

        floatx4 s[4];
        #pragma unroll
        for (int t = 0; t < 4; t++) {
            int row = t * 16 + cl;
            int sw = cl & 7;
            short8 bk0 = *reinterpret_cast<const short8*>(&Ktile[buf][row][(part ^ sw) * 8]);
            short8 bk1 = *reinterpret_cast<const short8*>(&Ktile[buf][row][((part + 4) ^ sw) * 8]);
            s[t] = __builtin_amdgcn_mfma_f32_16x16x32_bf16(aq0, bk0, zz, 0, 0, 0);
            s[t] = __builtin_amdgcn_mfma_f32_16x16x32_bf16(aq1, bk1, s[t], 0, 0, 0);
        }
        #pragma unroll
        for (int t = 0; t < 4; t++)
            #pragma unroll
            for (int j = 0; j < 4; j++) {
                float e = exp2f(s[t][j] * SCALE_L2E);
                es[j] += e;
                pbuf[wid][r0 + j][t * 16 + cl] = f2bf(e);
            }
        short8 pa0 = *reinterpret_cast<const short8*>(&pbuf[wid][cl][ko]);
        short8 pa1 = *reinterpret_cast<const short8*>(&pbuf[wid][cl][32 + ko]);
        // PV: V direct from global/L2 (no staging, no swizzle)
        #pragma unroll
        for (int ct = 0; ct < 4; ct++) {
            const unsigned short* vrow = Vb + (size_t)(ct * 16 + cl) * NHW + m0;
            short8 bv0 = *reinterpret_cast<const short8*>(vrow + ko);
            short8 bv1 = *reinterpret_cast<const short8*>(vrow + 32 + ko);
            oacc[ct] = __builtin_amdgcn_mfma_f32_16x16x32_bf16(pa0, bv0, oacc[ct], 0, 0, 0);
            oacc[ct] = __builtin_amdgcn_mfma_f32_16x16x32_bf16(pa1, bv1, oacc[ct], 0, 0, 0);
        }
        __syncthreads();
        buf ^= 1;
    }

    #pragma unroll
    for (int off = 1; off < 16; off <<= 1)
        #pragma unroll
        for (int j = 0; j < 4; j++) es[j] += __shfl_xor(es[j], off);
    float ri[4];
    #pragma unroll
    for (int j = 0; j < 4; j++) ri[j] = 1.f / es[j];

    const float* o2b = o2 + bh * 64;
    #pragma unroll
    for (int ct = 0; ct < 4; ct++) {
        float o2v = o2b[ct * 16 + cl];
        #pragma unroll
        for (int j = 0; j < 4; j++)
            pbuf[wid][r0 + j][ct * 16 + cl] = f2bf(oacc[ct][j] * ri[j] + o2v);
    }
    short8 w0 = *reinterpret_cast<const short8*>(&pbuf[wid][cl][part * 16]);
    short8 w1 = *reinterpret_cast<const short8*>(&pbuf[wid][cl][part * 16 + 8]);
    unsigned short* dst = AO + ((size_t)b * NHW + n0 + cl) * NC + h * 64 + part * 16;
    *reinterpret_cast<short8*>(dst)     = w0;
    *reinterpret_cast<short8*>(dst + 8) = w1;
}

// ---------------------------------------------------------------- launcher

extern "C" void kernel_launch(void* const* d_in, const int* in_sizes, int n_in,
                              void* d_out, int out_size, void* d_ws, size_t ws_size,
                              hipStream_t stream) {
    const float* x    = (const float*)d_in[0];
    const float* t    = (const float*)d_in[1];
    const float* Wk   = (const float*)d_in[2];
    const float* Wq   = (const float*)d_in[3];
    const float* Wt_w = (const float*)d_in[4];
    const float* Wt_b = (const float*)d_in[5];
    const float* Wm   = (const float*)d_in[6];
    const float* Wv   = (const float*)d_in[7];
    const float* Wr_w = (const float*)d_in[8];
    const float* Wr_b = (const float*)d_in[9];
    float* out = (float*)d_out;
    char* ws = (char*)d_ws;

    unsigned short* xT      = (unsigned short*)(ws);
    unsigned short* Wqkm    = (unsigned short*)(ws + 9437184);
    unsigned short* Wv_bf   = (unsigned short*)(ws + 11010048);
    unsigned short* Wr_bf   = (unsigned short*)(ws + 11534336);
    float*          tm      = (float*)(ws + 12058624);
    float*          tmerge  = (float*)(ws + 12091392);
    unsigned short* QT      = (unsigned short*)(ws + 12124160);
    unsigned short* KT      = (unsigned short*)(ws + 21561344);
    unsigned short* WmT     = (unsigned short*)(ws + 30998528);   // 1 MB
    float*          Wvm_txt = (float*)(ws + 32047104);            // 1 MB
    unsigned short* Vv      = (unsigned short*)(ws + 40435712);
    float*          o2      = (float*)(ws + 49872896);
    unsigned short* AO      = xT;   // xT dead after k_cross_o2; alias for AO
    (void)in_sizes; (void)n_in; (void)out_size; (void)ws_size;

    k_prep_all<<<9216, 256, 0, stream>>>(Wq, Wk, Wv, Wr_w, Wm, x, Wqkm, Wv_bf, Wr_bf, WmT, xT);
    k_fold<<<32, 256, 0, stream>>>(Wv_bf, WmT, Wqkm, Wvm_txt);
    k_prep_t<<<dim3(16, 4), 256, 0, stream>>>(t, Wt_w, Wt_b, Wvm_txt, tm, tmerge);
    k_gemm_qkm<<<864, 256, 0, stream>>>(Wqkm, xT, tmerge, QT, KT, Vv);
    k_cross_o2<<<128, 256, 0, stream>>>(xT, Vv, tm, o2);
    k_attn<<<1152, 256, 0, stream>>>(QT, KT, Vv, o2, AO);
    k_gemm_final<<<288, 256, 0, stream>>>(Wr_bf, AO, Wr_b, out);
}

// Round 14
// 122.943 us; speedup vs baseline: 1.1673x; 1.1673x over previous
//
#include <hip/hip_runtime.h>
#include <cstdint>
#include <cstddef>

#define NB    16
#define NC    512
#define NHW   576
#define NTF   512
#define NHEAD 8
#define NCPH  64
#define ATT_SCALE 0.125f
#define SCALE_L2E 0.18033688011112042f   // 0.125 * log2(e)

typedef float  floatx4 __attribute__((ext_vector_type(4)));
typedef short  short8  __attribute__((ext_vector_type(8)));
typedef unsigned short ushortx4 __attribute__((ext_vector_type(4)));

__device__ __forceinline__ unsigned short f2bf(float f) {
    unsigned int u = __float_as_uint(f);
    u += 0x7fffu + ((u >> 16) & 1u);
    return (unsigned short)(u >> 16);
}
__device__ __forceinline__ float bf2f(unsigned short h) {
    return __uint_as_float(((unsigned int)h) << 16);
}

// ---------------------------------------------------------------- fused prep
__global__ void k_prep_all(const float* __restrict__ Wq, const float* __restrict__ Wk,
                           const float* __restrict__ Wv, const float* __restrict__ Wr,
                           const float* __restrict__ Wm, const float* __restrict__ x,
                           unsigned short* __restrict__ Wqkm,
                           unsigned short* __restrict__ Wv_bf,
                           unsigned short* __restrict__ Wr_bf,
                           unsigned short* __restrict__ WmT,
                           unsigned short* __restrict__ xT) {
    __shared__ float tile[32][33];
    int bid = blockIdx.x;
    int tid = threadIdx.x;

    if (bid < 4096) {
        int i = bid * 256 + tid;
        if (i < 1024 * 512) {
            int r = i >> 9, c = i & 511;
            float v = (r < 512) ? Wq[r * 512 + c] : Wk[(r - 512) * 512 + c];
            Wqkm[i] = f2bf(v);
        } else {
            int j = i - 1024 * 512;
            if (j < 512 * 512) Wv_bf[j] = f2bf(Wv[j]);
            else               Wr_bf[j - 512 * 512] = f2bf(Wr[j - 512 * 512]);
        }
        return;
    }

    int tx = tid & 31, ty = tid >> 5;
    if (bid < 4608) {
        int bi = bid - 4096;                  // 0..511
        int n0 = (bi & 31) * 32, k0 = (bi >> 5) * 32;
        #pragma unroll
        for (int k = 0; k < 4; k++)
            tile[ty + k * 8][tx] = Wm[(size_t)(k0 + ty + k * 8) * 1024 + n0 + tx];
        __syncthreads();
        #pragma unroll
        for (int k = 0; k < 4; k++)
            WmT[(size_t)(n0 + ty + k * 8) * 512 + k0 + tx] = f2bf(tile[tx][ty + k * 8]);
        return;
    }

    int bi = bid - 4608;                      // 0..4607
    int pi = bi % 18, rem = bi / 18;
    int ci = rem & 15, b = rem >> 4;
    int p0 = pi * 32, c0 = ci * 32;
    const float* xb = x + (size_t)b * NC * NHW;
    #pragma unroll
    for (int k = 0; k < 4; k++)
        tile[ty + k * 8][tx] = xb[(size_t)(c0 + ty + k * 8) * NHW + p0 + tx];
    __syncthreads();
    unsigned short* xTb = xT + (size_t)b * NHW * NC;
    #pragma unroll
    for (int k = 0; k < 4; k++)
        xTb[(size_t)(p0 + ty + k * 8) * NC + c0 + tx] = f2bf(tile[tx][ty + k * 8]);
}

// tm[b][o] = dot(Wt_w[o], t[b]) + Wt_b[o];  tmerge[b][o] = dot(Wvm_txt[o], t[b])
__global__ void k_prep_t(const float* __restrict__ t, const float* __restrict__ Wt_w,
                         const float* __restrict__ Wt_b, const float* __restrict__ Wvm_txt,
                         float* __restrict__ tm, float* __restrict__ tmerge) {
    __shared__ float ts[512];
    int b = blockIdx.x;
    int tid = threadIdx.x;
    ts[tid]       = t[b * 512 + tid];
    ts[tid + 256] = t[b * 512 + tid + 256];
    __syncthreads();
    int oo = blockIdx.y * 256 + tid;
    const float* Wrow = (oo < 512) ? (Wt_w + (size_t)oo * 512)
                                   : (Wvm_txt + (size_t)(oo - 512) * 512);
    float acc = 0.f;
    #pragma unroll 4
    for (int c = 0; c < 512; c += 4) {
        float4 w = *reinterpret_cast<const float4*>(Wrow + c);
        acc += w.x * ts[c] + w.y * ts[c + 1] + w.z * ts[c + 2] + w.w * ts[c + 3];
    }
    if (oo < 512) tm[b * 512 + oo] = acc + Wt_b[oo];
    else          tmerge[b * 512 + (oo - 512)] = acc;
}

// ---------------------------------------------------------------- 128x128 LDS-staged GEMM core

__device__ __forceinline__ void g128_stage(const unsigned short* __restrict__ src,
                                           unsigned short* lds, int tid) {
    int row  = tid >> 3;
    int slot = (tid & 7) ^ (row & 7);
    #pragma unroll
    for (int i = 0; i < 4; i++) {
        __builtin_amdgcn_global_load_lds(
            (const __attribute__((address_space(1))) unsigned int*)(src + (size_t)(32 * i + row) * NC + slot * 8),
            (__attribute__((address_space(3))) unsigned int*)(lds + i * 2048 + tid * 8), 16, 0, 0);
    }
}

__device__ __forceinline__ void g128_main(const unsigned short* __restrict__ Asrc,
                                          const unsigned short* __restrict__ Bsrc,
                                          unsigned short (*At)[8192], unsigned short (*Bt)[8192],
                                          int tid, int lane, int wr, int wc,
                                          floatx4 (&acc)[4][4]) {
    int cl = lane & 15, hi = lane >> 4, sx = cl & 7;

    g128_stage(Asrc, At[0], tid);
    g128_stage(Bsrc, Bt[0], tid);
    __syncthreads();

    int buf = 0;
    for (int ks = 0; ks < 8; ks++) {
        if (ks < 7) {
            g128_stage(Asrc + (ks + 1) * 64, At[buf ^ 1], tid);
            g128_stage(Bsrc + (ks + 1) * 64, Bt[buf ^ 1], tid);
        }
        #pragma unroll
        for (int kk = 0; kk < 2; kk++) {
            int sl = ((kk << 2) + hi) ^ sx;
            short8 a[4], bb[4];
            #pragma unroll
            for (int i = 0; i < 4; i++)
                a[i] = *reinterpret_cast<const short8*>(&At[buf][(wr * 64 + i * 16 + cl) * 64 + sl * 8]);
            #pragma unroll
            for (int j = 0; j < 4; j++)
                bb[j] = *reinterpret_cast<const short8*>(&Bt[buf][(wc * 64 + j * 16 + cl) * 64 + sl * 8]);
            #pragma unroll
            for (int i = 0; i < 4; i++)
                #pragma unroll
                for (int j = 0; j < 4; j++)
                    acc[i][j] = __builtin_amdgcn_mfma_f32_16x16x32_bf16(a[i], bb[j], acc[i][j], 0, 0, 0);
        }
        __syncthreads();
        buf ^= 1;
    }
}

// Wvm = Wv @ Wm  (via WmT): cols 0..511 -> bf16 Wqkm rows 1024+, cols 512+ -> f32 Wvm_txt.
__global__ void k_fold(const unsigned short* __restrict__ Wv_bf,
                       const unsigned short* __restrict__ WmT,
                       unsigned short* __restrict__ Wqkm,
                       float* __restrict__ Wvm_txt) {
    __shared__ unsigned short At[2][8192], Bt[2][8192];
    int tid = threadIdx.x, lane = tid & 63, wid = tid >> 6;
    int wr = wid >> 1, wc = wid & 1;
    int m = blockIdx.x >> 3, nt = blockIdx.x & 7;
    int o0 = m * 128, n0 = nt * 128;

    floatx4 acc[4][4];
    floatx4 zz = {0.f, 0.f, 0.f, 0.f};
    #pragma unroll
    for (int i = 0; i < 4; i++)
        #pragma unroll
        for (int j = 0; j < 4; j++) acc[i][j] = zz;

    g128_main(Wv_bf + (size_t)o0 * NC, WmT + (size_t)n0 * NC, At, Bt, tid, lane, wr, wc, acc);

    int cl = lane & 15, r0 = (lane >> 4) * 4;
    #pragma unroll
    for (int i = 0; i < 4; i++)
        #pragma unroll
        for (int jn = 0; jn < 4; jn++) {
            int n = n0 + wc * 64 + jn * 16 + cl;
            #pragma unroll
            for (int j = 0; j < 4; j++) {
                int o = o0 + wr * 64 + i * 16 + r0 + j;
                if (n0 < 512) Wqkm[(size_t)(1024 + o) * 512 + n] = f2bf(acc[i][jn][j]);
                else          Wvm_txt[(size_t)o * 512 + (n - 512)] = acc[i][jn][j];
            }
        }
}

// Y = Wstack @ xT^T.  m<8: QT/KT transposed [n][o_local]; m>=8: V natural [b][c][p] + tmerge bias.
__global__ void k_gemm_qkm(const unsigned short* __restrict__ Wqkm,
                           const unsigned short* __restrict__ xT,
                           const float* __restrict__ tmerge,
                           unsigned short* __restrict__ QT,
                           unsigned short* __restrict__ KT,
                           unsigned short* __restrict__ V) {
    __shared__ unsigned short At[2][8192], Bt[2][8192];
    int tid = threadIdx.x, lane = tid & 63, wid = tid >> 6;
    int wr = wid >> 1, wc = wid & 1;
    int bid = blockIdx.x;
    int xcd = bid & 7, slot = bid >> 3;
    int m = slot / 9, nl = slot % 9;
    int n0 = (xcd * 9 + nl) * 128;
    int o0 = m * 128;

    floatx4 acc[4][4];
    floatx4 zz = {0.f, 0.f, 0.f, 0.f};
    #pragma unroll
    for (int i = 0; i < 4; i++)
        #pragma unroll
        for (int j = 0; j < 4; j++) acc[i][j] = zz;

    g128_main(Wqkm + (size_t)o0 * NC, xT + (size_t)n0 * NC, At, Bt, tid, lane, wr, wc, acc);

    int cl = lane & 15, r0 = (lane >> 4) * 4;
    int ob = (m & 3) * 128 + wr * 64;

    if (m < 8) {
        unsigned short* Yt = (m < 4) ? QT : KT;
        #pragma unroll
        for (int i = 0; i < 4; i++) {
            int ol = ob + i * 16 + r0;
            #pragma unroll
            for (int jn = 0; jn < 4; jn++) {
                int n = n0 + wc * 64 + jn * 16 + cl;
                ushortx4 pk;
                pk[0] = f2bf(acc[i][jn][0]);
                pk[1] = f2bf(acc[i][jn][1]);
                pk[2] = f2bf(acc[i][jn][2]);
                pk[3] = f2bf(acc[i][jn][3]);
                *reinterpret_cast<ushortx4*>(Yt + (size_t)n * NC + ol) = pk;
            }
        }
    } else {
        #pragma unroll
        for (int i = 0; i < 4; i++) {
            int ol = ob + i * 16 + r0;
            #pragma unroll
            for (int jn = 0; jn < 4; jn++) {
                int n = n0 + wc * 64 + jn * 16 + cl;
                int b = n / NHW, p = n - b * NHW;
                float4 tv = *reinterpret_cast<const float4*>(tmerge + b * NC + ol);
                float bias[4] = {tv.x, tv.y, tv.z, tv.w};
                #pragma unroll
                for (int j = 0; j < 4; j++)
                    V[((size_t)b * NC + ol + j) * NHW + p] = f2bf(acc[i][jn][j] + bias[j]);
            }
        }
    }
}

// out = Wr @ AO^T + Wr_b -> natural f32 [b][o][p].
// Epilogue: LDS-staged transpose (aliasing the dead staging buffers) ->
// coalesced float4 stores along p. 576 % 4 == 0 so no float4 straddles b.
__global__ void k_gemm_final(const unsigned short* __restrict__ Wr_bf,
                             const unsigned short* __restrict__ AO,
                             const float* __restrict__ Wr_b,
                             float* __restrict__ out) {
    __shared__ unsigned short smem[32768];   // 64 KB: staging dbuf, then f32 C-stage
    unsigned short (*At)[8192] = (unsigned short (*)[8192])(smem);
    unsigned short (*Bt)[8192] = (unsigned short (*)[8192])(smem + 16384);
    int tid = threadIdx.x, lane = tid & 63, wid = tid >> 6;
    int wr = wid >> 1, wc = wid & 1;
    int bid = blockIdx.x;
    int xcd = bid & 7, slot = bid >> 3;
    int m = slot / 9, nl = slot % 9;
    int n0 = (xcd * 9 + nl) * 128;
    int o0 = m * 128;

    floatx4 acc[4][4];
    floatx4 zz = {0.f, 0.f, 0.f, 0.f};
    #pragma unroll
    for (int i = 0; i < 4; i++)
        #pragma unroll
        for (int j = 0; j < 4; j++) acc[i][j] = zz;

    g128_main(Wr_bf + (size_t)o0 * NC, AO + (size_t)n0 * NC, At, Bt, tid, lane, wr, wc, acc);

    float* fs = (float*)smem;                // [64][132] f32 = 33792 B
    int cl = lane & 15, r0 = (lane >> 4) * 4;
    #pragma unroll
    for (int pass = 0; pass < 2; pass++) {
        if (pass) __syncthreads();           // protect fs from previous read phase
        if (wr == pass) {
            #pragma unroll
            for (int i = 0; i < 4; i++) {
                float4 bv = *reinterpret_cast<const float4*>(Wr_b + o0 + wr * 64 + i * 16 + r0);
                #pragma unroll
                for (int jn = 0; jn < 4; jn++) {
                    int ncol = wc * 64 + jn * 16 + cl;
                    fs[(i * 16 + r0 + 0) * 132 + ncol] = acc[i][jn][0] + bv.x;
                    fs[(i * 16 + r0 + 1) * 132 + ncol] = acc[i][jn][1] + bv.y;
                    fs[(i * 16 + r0 + 2) * 132 + ncol] = acc[i][jn][2] + bv.z;
                    fs[(i * 16 + r0 + 3) * 132 + ncol] = acc[i][jn][3] + bv.w;
                }
            }
        }
        __syncthreads();
        int row = tid >> 2, quad = tid & 3;  // 64 rows x 4 col-quads
        int c = o0 + pass * 64 + row;
        #pragma unroll
        for (int k = 0; k < 8; k++) {
            int ncol = quad * 32 + k * 4;
            float4 v = *reinterpret_cast<const float4*>(&fs[row * 132 + ncol]);
            int n = n0 + ncol;
            int b = n / NHW, p = n - b * NHW;
            *reinterpret_cast<float4*>(&out[((size_t)b * NC + c) * NHW + p]) = v;
        }
    }
}

// ---------------------------------------------------------------- cross + o2

__global__ void k_cross_o2(const unsigned short* __restrict__ xT,
                           const unsigned short* __restrict__ V,
                           const float* __restrict__ tm,
                           float* __restrict__ o2) {
    __shared__ float tms[64];
    __shared__ float ss[576];
    __shared__ float red[8];
    __shared__ float part[4][64];
    int bh = blockIdx.x;
    int b = bh >> 3, h = bh & 7;
    int tid = threadIdx.x;

    if (tid < 64) tms[tid] = tm[b * 512 + h * 64 + tid];
    __syncthreads();

    for (int m = tid; m < 576; m += 256) {
        const short8* xr8 = reinterpret_cast<const short8*>(xT + ((size_t)b * NHW + m) * NC + h * 64);
        float acc = 0.f;
        #pragma unroll
        for (int cc = 0; cc < 8; cc++) {
            short8 v8 = xr8[cc];
            #pragma unroll
            for (int q = 0; q < 8; q++)
                acc += bf2f((unsigned short)v8[q]) * tms[cc * 8 + q];
        }
        ss[m] = acc * ATT_SCALE;
    }
    __syncthreads();

    float pmax = -3e38f;
    for (int m = tid; m < 576; m += 256) pmax = fmaxf(pmax, ss[m]);
    #pragma unroll
    for (int off = 32; off; off >>= 1) pmax = fmaxf(pmax, __shfl_xor(pmax, off));
    if ((tid & 63) == 0) red[tid >> 6] = pmax;
    __syncthreads();
    float mx = fmaxf(fmaxf(red[0], red[1]), fmaxf(red[2], red[3]));

    float psum = 0.f;
    for (int m = tid; m < 576; m += 256) {
        float e = __expf(ss[m] - mx);
        ss[m] = e;
        psum += e;
    }
    #pragma unroll
    for (int off = 32; off; off >>= 1) psum += __shfl_xor(psum, off);
    if ((tid & 63) == 0) red[4 + (tid >> 6)] = psum;
    __syncthreads();
    float inv = 1.f / (red[4] + red[5] + red[6] + red[7]);

    // o2 partial: vectorized short8 V reads (144 elems = 18 x short8, 16B-aligned)
    int c = tid & 63, seg = tid >> 6;
    const short8* vp = reinterpret_cast<const short8*>(
        V + ((size_t)b * NC + h * 64 + c) * NHW + seg * 144);
    float pa = 0.f;
    #pragma unroll 2
    for (int mm = 0; mm < 18; mm++) {
        short8 v8 = vp[mm];
        int mbase = seg * 144 + mm * 8;
        #pragma unroll
        for (int q = 0; q < 8; q++)
            pa += bf2f((unsigned short)v8[q]) * ss[mbase + q];
    }
    part[seg][c] = pa;
    __syncthreads();
    if (tid < 64)
        o2[(b * 8 + h) * 64 + tid] =
            (part[0][tid] + part[1][tid] + part[2][tid] + part[3][tid]) * inv;
}

// ---------------------------------------------------------------- attention core
// (measured-good v9: 4 waves x 16 q-rows, grid 1152, XCD-grouped, cooperative
// global_load_lds double-buffered K+V staging, XOR-swizzled tiles)

__global__ void k_attn(const unsigned short* __restrict__ QT,
                       const unsigned short* __restrict__ KT,
                       const unsigned short* __restrict__ V,
                       const float* __restrict__ o2,
                       unsigned short* __restrict__ AO) {
    __shared__ unsigned short Ktile[2][64][64];
    __shared__ unsigned short Vtile[2][64][64];
    __shared__ unsigned short pbuf[4][16][88];
    int tid  = threadIdx.x;
    int lane = tid & 63, wid = tid >> 6;

    int bid  = blockIdx.x;
    int xcd  = bid & 7;
    int slot = bid >> 3;
    int bh   = xcd * 16 + slot / 9;
    int qt   = slot % 9;
    int b = bh >> 3, h = bh & 7;
    int n0 = qt * 64 + wid * 16;
    int cl = lane & 15;
    int r0 = (lane >> 4) * 4;
    int part = lane >> 4;
    int ko = part * 8;

    const unsigned short* Qb = QT + ((size_t)b * NHW + n0) * NC + h * 64;
    const unsigned short* Kb = KT + (size_t)b * NHW * NC + h * 64;
    const unsigned short* Vb = V  + ((size_t)b * NC + h * 64) * NHW;

    short8 aq0 = *reinterpret_cast<const short8*>(Qb + (size_t)cl * NC + ko);
    short8 aq1 = *reinterpret_cast<const short8*>(Qb + (size_t)cl * NC + 32 + ko);

    int srow = lane >> 3;
    int scol = (lane & 7) ^ srow;

    floatx4 zz = {0.f, 0.f, 0.f, 0.f};
    floatx4 oacc[4] = {zz, zz, zz, zz};
    float es[4] = {0.f, 0.f, 0.f, 0.f};

    {
        const unsigned short* ks = Kb + (size_t)(wid * 16 + srow) * NC + scol * 8;
        const unsigned short* vs = Vb + (size_t)(wid * 16 + srow) * NHW + scol * 8;
        #pragma unroll
        for (int i = 0; i < 2; i++) {
            __builtin_amdgcn_global_load_lds(
                (const __attribute__((address_space(1))) unsigned int*)(ks + (size_t)i * 8 * NC),
                (__attribute__((address_space(3))) unsigned int*)&Ktile[0][wid * 16 + i * 8][0], 16, 0, 0);
            __builtin_amdgcn_global_load_lds(
                (const __attribute__((address_space(1))) unsigned int*)(vs + (size_t)i * 8 * NHW),
                (__attribute__((address_space(3))) unsigned int*)&Vtile[0][wid * 16 + i * 8][0], 16, 0, 0);
        }
    }
    __syncthreads();

    int buf = 0;
    for (int chk = 0; chk < 9; chk++) {
        int m0 = chk * 64;
        if (chk < 8) {
            const unsigned short* ks = Kb + (size_t)(m0 + 64 + wid * 16 + srow) * NC + scol * 8;
            const unsigned short* vs = Vb + (size_t)(wid * 16 + srow) * NHW + (m0 + 64) + scol * 8;
            #pragma unroll
            for (int i = 0; i < 2; i++) {
                __builtin_amdgcn_global_load_lds(
                    (const __attribute__((address_space(1))) unsigned int*)(ks + (size_t)i * 8 * NC),
                    (__attribute__((address_space(3))) unsigned int*)&Ktile[buf ^ 1][wid * 16 + i * 8][0], 16, 0, 0);
                __builtin_amdgcn_global_load_lds(
                    (const __attribute__((address_space(1))) unsigned int*)(vs + (size_t)i * 8 * NHW),
                    (__attribute__((address_space(3))) unsigned int*)&Vtile[buf ^ 1][wid * 16 + i * 8][0], 16, 0, 0);
            }
        }

        floatx4 s[4];
        #pragma unroll
        for (int t = 0; t < 4; t++) {
            int row = t * 16 + cl;
            int sw = cl & 7;
            short8 bk0 = *reinterpret_cast<const short8*>(&Ktile[buf][row][(part ^ sw) * 8]);
            short8 bk1 = *reinterpret_cast<const short8*>(&Ktile[buf][row][((part + 4) ^ sw) * 8]);
            s[t] = __builtin_amdgcn_mfma_f32_16x16x32_bf16(aq0, bk0, zz, 0, 0, 0);
            s[t] = __builtin_amdgcn_mfma_f32_16x16x32_bf16(aq1, bk1, s[t], 0, 0, 0);
        }
        #pragma unroll
        for (int t = 0; t < 4; t++)
            #pragma unroll
            for (int j = 0; j < 4; j++) {
                float e = exp2f(s[t][j] * SCALE_L2E);
                es[j] += e;
                pbuf[wid][r0 + j][t * 16 + cl] = f2bf(e);
            }
        short8 pa0 = *reinterpret_cast<const short8*>(&pbuf[wid][cl][ko]);
        short8 pa1 = *reinterpret_cast<const short8*>(&pbuf[wid][cl][32 + ko]);
        #pragma unroll
        for (int ct = 0; ct < 4; ct++) {
            int row = ct * 16 + cl;
            int sw = cl & 7;
            short8 bv0 = *reinterpret_cast<const short8*>(&Vtile[buf][row][(part ^ sw) * 8]);
            short8 bv1 = *reinterpret_cast<const short8*>(&Vtile[buf][row][((part + 4) ^ sw) * 8]);
            oacc[ct] = __builtin_amdgcn_mfma_f32_16x16x32_bf16(pa0, bv0, oacc[ct], 0, 0, 0);
            oacc[ct] = __builtin_amdgcn_mfma_f32_16x16x32_bf16(pa1, bv1, oacc[ct], 0, 0, 0);
        }
        __syncthreads();
        buf ^= 1;
    }

    #pragma unroll
    for (int off = 1; off < 16; off <<= 1)
        #pragma unroll
        for (int j = 0; j < 4; j++) es[j] += __shfl_xor(es[j], off);
    float ri[4];
    #pragma unroll
    for (int j = 0; j < 4; j++) ri[j] = 1.f / es[j];

    const float* o2b = o2 + bh * 64;
    #pragma unroll
    for (int ct = 0; ct < 4; ct++) {
        float o2v = o2b[ct * 16 + cl];
        #pragma unroll
        for (int j = 0; j < 4; j++)
            pbuf[wid][r0 + j][ct * 16 + cl] = f2bf(oacc[ct][j] * ri[j] + o2v);
    }
    short8 w0 = *reinterpret_cast<const short8*>(&pbuf[wid][cl][part * 16]);
    short8 w1 = *reinterpret_cast<const short8*>(&pbuf[wid][cl][part * 16 + 8]);
    unsigned short* dst = AO + ((size_t)b * NHW + n0 + cl) * NC + h * 64 + part * 16;
    *reinterpret_cast<short8*>(dst)     = w0;
    *reinterpret_cast<short8*>(dst + 8) = w1;
}

// ---------------------------------------------------------------- launcher

extern "C" void kernel_launch(void* const* d_in, const int* in_sizes, int n_in,
                              void* d_out, int out_size, void* d_ws, size_t ws_size,
                              hipStream_t stream) {
    const float* x    = (const float*)d_in[0];
    const float* t    = (const float*)d_in[1];
    const float* Wk   = (const float*)d_in[2];
    const float* Wq   = (const float*)d_in[3];
    const float* Wt_w = (const float*)d_in[4];
    const float* Wt_b = (const float*)d_in[5];
    const float* Wm   = (const float*)d_in[6];
    const float* Wv   = (const float*)d_in[7];
    const float* Wr_w = (const float*)d_in[8];
    const float* Wr_b = (const float*)d_in[9];
    float* out = (float*)d_out;
    char* ws = (char*)d_ws;

    unsigned short* xT      = (unsigned short*)(ws);
    unsigned short* Wqkm    = (unsigned short*)(ws + 9437184);
    unsigned short* Wv_bf   = (unsigned short*)(ws + 11010048);
    unsigned short* Wr_bf   = (unsigned short*)(ws + 11534336);
    float*          tm      = (float*)(ws + 12058624);
    float*          tmerge  = (float*)(ws + 12091392);
    unsigned short* QT      = (unsigned short*)(ws + 12124160);
    unsigned short* KT      = (unsigned short*)(ws + 21561344);
    unsigned short* WmT     = (unsigned short*)(ws + 30998528);   // 1 MB
    float*          Wvm_txt = (float*)(ws + 32047104);            // 1 MB
    unsigned short* Vv      = (unsigned short*)(ws + 40435712);
    float*          o2      = (float*)(ws + 49872896);
    unsigned short* AO      = xT;   // xT dead after k_cross_o2; alias for AO
    (void)in_sizes; (void)n_in; (void)out_size; (void)ws_size;

    k_prep_all<<<9216, 256, 0, stream>>>(Wq, Wk, Wv, Wr_w, Wm, x, Wqkm, Wv_bf, Wr_bf, WmT, xT);
    k_fold<<<32, 256, 0, stream>>>(Wv_bf, WmT, Wqkm, Wvm_txt);
    k_prep_t<<<dim3(16, 4), 256, 0, stream>>>(t, Wt_w, Wt_b, Wvm_txt, tm, tmerge);
    k_gemm_qkm<<<864, 256, 0, stream>>>(Wqkm, xT, tmerge, QT, KT, Vv);
    k_cross_o2<<<128, 256, 0, stream>>>(xT, Vv, tm, o2);
    k_attn<<<1152, 256, 0, stream>>>(QT, KT, Vv, o2, AO);
    k_gemm_final<<<288, 256, 0, stream>>>(Wr_bf, AO, Wr_b, out);
}

// Round 16
// 118.307 us; speedup vs baseline: 1.2130x; 1.0392x over previous
//
#include <hip/hip_runtime.h>
#include <cstdint>
#include <cstddef>

#define NB    16
#define NC    512
#define NHW   576
#define NTF   512
#define NHEAD 8
#define NCPH  64
#define ATT_SCALE 0.125f
#define SCALE_L2E 0.18033688011112042f   // 0.125 * log2(e)

typedef float  floatx4 __attribute__((ext_vector_type(4)));
typedef short  short8  __attribute__((ext_vector_type(8)));
typedef unsigned short ushortx4 __attribute__((ext_vector_type(4)));

__device__ __forceinline__ unsigned short f2bf(float f) {
    unsigned int u = __float_as_uint(f);
    u += 0x7fffu + ((u >> 16) & 1u);
    return (unsigned short)(u >> 16);
}
__device__ __forceinline__ float bf2f(unsigned short h) {
    return __uint_as_float(((unsigned int)h) << 16);
}

// ---------------------------------------------------------------- fused prep
__global__ void k_prep_all(const float* __restrict__ Wq, const float* __restrict__ Wk,
                           const float* __restrict__ Wv, const float* __restrict__ Wr,
                           const float* __restrict__ Wm, const float* __restrict__ x,
                           unsigned short* __restrict__ Wqkm,
                           unsigned short* __restrict__ Wv_bf,
                           unsigned short* __restrict__ Wr_bf,
                           unsigned short* __restrict__ WmT,
                           unsigned short* __restrict__ xT) {
    __shared__ float tile[32][33];
    int bid = blockIdx.x;
    int tid = threadIdx.x;

    if (bid < 4096) {
        int i = bid * 256 + tid;
        if (i < 1024 * 512) {
            int r = i >> 9, c = i & 511;
            float v = (r < 512) ? Wq[r * 512 + c] : Wk[(r - 512) * 512 + c];
            Wqkm[i] = f2bf(v);
        } else {
            int j = i - 1024 * 512;
            if (j < 512 * 512) Wv_bf[j] = f2bf(Wv[j]);
            else               Wr_bf[j - 512 * 512] = f2bf(Wr[j - 512 * 512]);
        }
        return;
    }

    int tx = tid & 31, ty = tid >> 5;
    if (bid < 4608) {
        int bi = bid - 4096;                  // 0..511
        int n0 = (bi & 31) * 32, k0 = (bi >> 5) * 32;
        #pragma unroll
        for (int k = 0; k < 4; k++)
            tile[ty + k * 8][tx] = Wm[(size_t)(k0 + ty + k * 8) * 1024 + n0 + tx];
        __syncthreads();
        #pragma unroll
        for (int k = 0; k < 4; k++)
            WmT[(size_t)(n0 + ty + k * 8) * 512 + k0 + tx] = f2bf(tile[tx][ty + k * 8]);
        return;
    }

    int bi = bid - 4608;                      // 0..4607
    int pi = bi % 18, rem = bi / 18;
    int ci = rem & 15, b = rem >> 4;
    int p0 = pi * 32, c0 = ci * 32;
    const float* xb = x + (size_t)b * NC * NHW;
    #pragma unroll
    for (int k = 0; k < 4; k++)
        tile[ty + k * 8][tx] = xb[(size_t)(c0 + ty + k * 8) * NHW + p0 + tx];
    __syncthreads();
    unsigned short* xTb = xT + (size_t)b * NHW * NC;
    #pragma unroll
    for (int k = 0; k < 4; k++)
        xTb[(size_t)(p0 + ty + k * 8) * NC + c0 + tx] = f2bf(tile[tx][ty + k * 8]);
}

// tm[b][o] = dot(Wt_w[o], t[b]) + Wt_b[o];  tmerge[b][o] = dot(Wvm_txt[o], t[b])
__global__ void k_prep_t(const float* __restrict__ t, const float* __restrict__ Wt_w,
                         const float* __restrict__ Wt_b, const float* __restrict__ Wvm_txt,
                         float* __restrict__ tm, float* __restrict__ tmerge) {
    __shared__ float ts[512];
    int b = blockIdx.x;
    int tid = threadIdx.x;
    ts[tid]       = t[b * 512 + tid];
    ts[tid + 256] = t[b * 512 + tid + 256];
    __syncthreads();
    int oo = blockIdx.y * 256 + tid;
    const float* Wrow = (oo < 512) ? (Wt_w + (size_t)oo * 512)
                                   : (Wvm_txt + (size_t)(oo - 512) * 512);
    float acc = 0.f;
    #pragma unroll 4
    for (int c = 0; c < 512; c += 4) {
        float4 w = *reinterpret_cast<const float4*>(Wrow + c);
        acc += w.x * ts[c] + w.y * ts[c + 1] + w.z * ts[c + 2] + w.w * ts[c + 3];
    }
    if (oo < 512) tm[b * 512 + oo] = acc + Wt_b[oo];
    else          tmerge[b * 512 + (oo - 512)] = acc;
}

// ---------------------------------------------------------------- 128x128 LDS-staged GEMM core

__device__ __forceinline__ void g128_stage(const unsigned short* __restrict__ src,
                                           unsigned short* lds, int tid) {
    int row  = tid >> 3;
    int slot = (tid & 7) ^ (row & 7);
    #pragma unroll
    for (int i = 0; i < 4; i++) {
        __builtin_amdgcn_global_load_lds(
            (const __attribute__((address_space(1))) unsigned int*)(src + (size_t)(32 * i + row) * NC + slot * 8),
            (__attribute__((address_space(3))) unsigned int*)(lds + i * 2048 + tid * 8), 16, 0, 0);
    }
}

__device__ __forceinline__ void g128_main(const unsigned short* __restrict__ Asrc,
                                          const unsigned short* __restrict__ Bsrc,
                                          unsigned short (*At)[8192], unsigned short (*Bt)[8192],
                                          int tid, int lane, int wr, int wc,
                                          floatx4 (&acc)[4][4]) {
    int cl = lane & 15, hi = lane >> 4, sx = cl & 7;

    g128_stage(Asrc, At[0], tid);
    g128_stage(Bsrc, Bt[0], tid);
    __syncthreads();

    int buf = 0;
    for (int ks = 0; ks < 8; ks++) {
        if (ks < 7) {
            g128_stage(Asrc + (ks + 1) * 64, At[buf ^ 1], tid);
            g128_stage(Bsrc + (ks + 1) * 64, Bt[buf ^ 1], tid);
        }
        #pragma unroll
        for (int kk = 0; kk < 2; kk++) {
            int sl = ((kk << 2) + hi) ^ sx;
            short8 a[4], bb[4];
            #pragma unroll
            for (int i = 0; i < 4; i++)
                a[i] = *reinterpret_cast<const short8*>(&At[buf][(wr * 64 + i * 16 + cl) * 64 + sl * 8]);
            #pragma unroll
            for (int j = 0; j < 4; j++)
                bb[j] = *reinterpret_cast<const short8*>(&Bt[buf][(wc * 64 + j * 16 + cl) * 64 + sl * 8]);
            #pragma unroll
            for (int i = 0; i < 4; i++)
                #pragma unroll
                for (int j = 0; j < 4; j++)
                    acc[i][j] = __builtin_amdgcn_mfma_f32_16x16x32_bf16(a[i], bb[j], acc[i][j], 0, 0, 0);
        }
        __syncthreads();
        buf ^= 1;
    }
}

// Wvm = Wv @ Wm  (via WmT): cols 0..511 -> bf16 Wqkm rows 1024+, cols 512+ -> f32 Wvm_txt.
__global__ void k_fold(const unsigned short* __restrict__ Wv_bf,
                       const unsigned short* __restrict__ WmT,
                       unsigned short* __restrict__ Wqkm,
                       float* __restrict__ Wvm_txt) {
    __shared__ unsigned short At[2][8192], Bt[2][8192];
    int tid = threadIdx.x, lane = tid & 63, wid = tid >> 6;
    int wr = wid >> 1, wc = wid & 1;
    int m = blockIdx.x >> 3, nt = blockIdx.x & 7;
    int o0 = m * 128, n0 = nt * 128;

    floatx4 acc[4][4];
    floatx4 zz = {0.f, 0.f, 0.f, 0.f};
    #pragma unroll
    for (int i = 0; i < 4; i++)
        #pragma unroll
        for (int j = 0; j < 4; j++) acc[i][j] = zz;

    g128_main(Wv_bf + (size_t)o0 * NC, WmT + (size_t)n0 * NC, At, Bt, tid, lane, wr, wc, acc);

    int cl = lane & 15, r0 = (lane >> 4) * 4;
    #pragma unroll
    for (int i = 0; i < 4; i++)
        #pragma unroll
        for (int jn = 0; jn < 4; jn++) {
            int n = n0 + wc * 64 + jn * 16 + cl;
            #pragma unroll
            for (int j = 0; j < 4; j++) {
                int o = o0 + wr * 64 + i * 16 + r0 + j;
                if (n0 < 512) Wqkm[(size_t)(1024 + o) * 512 + n] = f2bf(acc[i][jn][j]);
                else          Wvm_txt[(size_t)o * 512 + (n - 512)] = acc[i][jn][j];
            }
        }
}

// Y = Wstack @ xT^T.  m<8: QT/KT transposed [n][o_local]; m>=8: V natural [b][c][p] + tmerge bias.
__global__ void k_gemm_qkm(const unsigned short* __restrict__ Wqkm,
                           const unsigned short* __restrict__ xT,
                           const float* __restrict__ tmerge,
                           unsigned short* __restrict__ QT,
                           unsigned short* __restrict__ KT,
                           unsigned short* __restrict__ V) {
    __shared__ unsigned short At[2][8192], Bt[2][8192];
    int tid = threadIdx.x, lane = tid & 63, wid = tid >> 6;
    int wr = wid >> 1, wc = wid & 1;
    int bid = blockIdx.x;
    int xcd = bid & 7, slot = bid >> 3;
    int m = slot / 9, nl = slot % 9;
    int n0 = (xcd * 9 + nl) * 128;
    int o0 = m * 128;

    floatx4 acc[4][4];
    floatx4 zz = {0.f, 0.f, 0.f, 0.f};
    #pragma unroll
    for (int i = 0; i < 4; i++)
        #pragma unroll
        for (int j = 0; j < 4; j++) acc[i][j] = zz;

    g128_main(Wqkm + (size_t)o0 * NC, xT + (size_t)n0 * NC, At, Bt, tid, lane, wr, wc, acc);

    int cl = lane & 15, r0 = (lane >> 4) * 4;
    int ob = (m & 3) * 128 + wr * 64;

    if (m < 8) {
        unsigned short* Yt = (m < 4) ? QT : KT;
        #pragma unroll
        for (int i = 0; i < 4; i++) {
            int ol = ob + i * 16 + r0;
            #pragma unroll
            for (int jn = 0; jn < 4; jn++) {
                int n = n0 + wc * 64 + jn * 16 + cl;
                ushortx4 pk;
                pk[0] = f2bf(acc[i][jn][0]);
                pk[1] = f2bf(acc[i][jn][1]);
                pk[2] = f2bf(acc[i][jn][2]);
                pk[3] = f2bf(acc[i][jn][3]);
                *reinterpret_cast<ushortx4*>(Yt + (size_t)n * NC + ol) = pk;
            }
        }
    } else {
        #pragma unroll
        for (int i = 0; i < 4; i++) {
            int ol = ob + i * 16 + r0;
            #pragma unroll
            for (int jn = 0; jn < 4; jn++) {
                int n = n0 + wc * 64 + jn * 16 + cl;
                int b = n / NHW, p = n - b * NHW;
                float4 tv = *reinterpret_cast<const float4*>(tmerge + b * NC + ol);
                float bias[4] = {tv.x, tv.y, tv.z, tv.w};
                #pragma unroll
                for (int j = 0; j < 4; j++)
                    V[((size_t)b * NC + ol + j) * NHW + p] = f2bf(acc[i][jn][j] + bias[j]);
            }
        }
    }
}

// out = Wr @ AO^T + Wr_b -> natural f32 [b][o][p]  (v9 scatter epilogue).
__global__ void k_gemm_final(const unsigned short* __restrict__ Wr_bf,
                             const unsigned short* __restrict__ AO,
                             const float* __restrict__ Wr_b,
                             float* __restrict__ out) {
    __shared__ unsigned short At[2][8192], Bt[2][8192];
    int tid = threadIdx.x, lane = tid & 63, wid = tid >> 6;
    int wr = wid >> 1, wc = wid & 1;
    int bid = blockIdx.x;
    int xcd = bid & 7, slot = bid >> 3;
    int m = slot / 9, nl = slot % 9;
    int n0 = (xcd * 9 + nl) * 128;
    int o0 = m * 128;

    floatx4 acc[4][4];
    floatx4 zz = {0.f, 0.f, 0.f, 0.f};
    #pragma unroll
    for (int i = 0; i < 4; i++)
        #pragma unroll
        for (int j = 0; j < 4; j++) acc[i][j] = zz;

    g128_main(Wr_bf + (size_t)o0 * NC, AO + (size_t)n0 * NC, At, Bt, tid, lane, wr, wc, acc);

    int cl = lane & 15, r0 = (lane >> 4) * 4;
    #pragma unroll
    for (int i = 0; i < 4; i++) {
        float4 bv = *reinterpret_cast<const float4*>(Wr_b + o0 + wr * 64 + i * 16 + r0);
        float bias[4] = {bv.x, bv.y, bv.z, bv.w};
        #pragma unroll
        for (int jn = 0; jn < 4; jn++) {
            int n = n0 + wc * 64 + jn * 16 + cl;
            int b = n / NHW, p = n - b * NHW;
            #pragma unroll
            for (int j = 0; j < 4; j++) {
                int c = o0 + wr * 64 + i * 16 + r0 + j;
                out[((size_t)b * NC + c) * NHW + p] = acc[i][jn][j] + bias[j];
            }
        }
    }
}

// ---------------------------------------------------------------- cross + o2
// (v9 structure; PV pass vectorized to short8 loads — G13)

__global__ void k_cross_o2(const unsigned short* __restrict__ xT,
                           const unsigned short* __restrict__ V,
                           const float* __restrict__ tm,
                           float* __restrict__ o2) {
    __shared__ float tms[64];
    __shared__ float ss[576];
    __shared__ float red[8];
    __shared__ float part[4][64];
    int bh = blockIdx.x;
    int b = bh >> 3, h = bh & 7;
    int tid = threadIdx.x;

    if (tid < 64) tms[tid] = tm[b * 512 + h * 64 + tid];
    __syncthreads();

    for (int m = tid; m < 576; m += 256) {
        const short8* xr8 = reinterpret_cast<const short8*>(xT + ((size_t)b * NHW + m) * NC + h * 64);
        float acc = 0.f;
        #pragma unroll
        for (int cc = 0; cc < 8; cc++) {
            short8 v8 = xr8[cc];
            #pragma unroll
            for (int q = 0; q < 8; q++)
                acc += bf2f((unsigned short)v8[q]) * tms[cc * 8 + q];
        }
        ss[m] = acc * ATT_SCALE;
    }
    __syncthreads();

    float pmax = -3e38f;
    for (int m = tid; m < 576; m += 256) pmax = fmaxf(pmax, ss[m]);
    #pragma unroll
    for (int off = 32; off; off >>= 1) pmax = fmaxf(pmax, __shfl_xor(pmax, off));
    if ((tid & 63) == 0) red[tid >> 6] = pmax;
    __syncthreads();
    float mx = fmaxf(fmaxf(red[0], red[1]), fmaxf(red[2], red[3]));

    float psum = 0.f;
    for (int m = tid; m < 576; m += 256) {
        float e = __expf(ss[m] - mx);
        ss[m] = e;
        psum += e;
    }
    #pragma unroll
    for (int off = 32; off; off >>= 1) psum += __shfl_xor(psum, off);
    if ((tid & 63) == 0) red[4 + (tid >> 6)] = psum;
    __syncthreads();
    float inv = 1.f / (red[4] + red[5] + red[6] + red[7]);

    // o2 partial: vectorized short8 V reads (144 elems = 18 x short8, 16B-aligned)
    int c = tid & 63, seg = tid >> 6;
    const short8* vp = reinterpret_cast<const short8*>(
        V + ((size_t)b * NC + h * 64 + c) * NHW + seg * 144);
    float pa = 0.f;
    #pragma unroll 2
    for (int mm = 0; mm < 18; mm++) {
        short8 v8 = vp[mm];
        int mbase = seg * 144 + mm * 8;
        #pragma unroll
        for (int q = 0; q < 8; q++)
            pa += bf2f((unsigned short)v8[q]) * ss[mbase + q];
    }
    part[seg][c] = pa;
    __syncthreads();
    if (tid < 64)
        o2[(b * 8 + h) * 64 + tid] =
            (part[0][tid] + part[1][tid] + part[2][tid] + part[3][tid]) * inv;
}

// ---------------------------------------------------------------- attention core
// (measured-good v9: 4 waves x 16 q-rows, grid 1152, XCD-grouped, cooperative
// global_load_lds double-buffered K+V staging, XOR-swizzled tiles)

__global__ void k_attn(const unsigned short* __restrict__ QT,
                       const unsigned short* __restrict__ KT,
                       const unsigned short* __restrict__ V,
                       const float* __restrict__ o2,
                       unsigned short* __restrict__ AO) {
    __shared__ unsigned short Ktile[2][64][64];
    __shared__ unsigned short Vtile[2][64][64];
    __shared__ unsigned short pbuf[4][16][88];
    int tid  = threadIdx.x;
    int lane = tid & 63, wid = tid >> 6;

    int bid  = blockIdx.x;
    int xcd  = bid & 7;
    int slot = bid >> 3;
    int bh   = xcd * 16 + slot / 9;
    int qt   = slot % 9;
    int b = bh >> 3, h = bh & 7;
    int n0 = qt * 64 + wid * 16;
    int cl = lane & 15;
    int r0 = (lane >> 4) * 4;
    int part = lane >> 4;
    int ko = part * 8;

    const unsigned short* Qb = QT + ((size_t)b * NHW + n0) * NC + h * 64;
    const unsigned short* Kb = KT + (size_t)b * NHW * NC + h * 64;
    const unsigned short* Vb = V  + ((size_t)b * NC + h * 64) * NHW;

    short8 aq0 = *reinterpret_cast<const short8*>(Qb + (size_t)cl * NC + ko);
    short8 aq1 = *reinterpret_cast<const short8*>(Qb + (size_t)cl * NC + 32 + ko);

    int srow = lane >> 3;
    int scol = (lane & 7) ^ srow;

    floatx4 zz = {0.f, 0.f, 0.f, 0.f};
    floatx4 oacc[4] = {zz, zz, zz, zz};
    float es[4] = {0.f, 0.f, 0.f, 0.f};

    {
        const unsigned short* ks = Kb + (size_t)(wid * 16 + srow) * NC + scol * 8;
        const unsigned short* vs = Vb + (size_t)(wid * 16 + srow) * NHW + scol * 8;
        #pragma unroll
        for (int i = 0; i < 2; i++) {
            __builtin_amdgcn_global_load_lds(
                (const __attribute__((address_space(1))) unsigned int*)(ks + (size_t)i * 8 * NC),
                (__attribute__((address_space(3))) unsigned int*)&Ktile[0][wid * 16 + i * 8][0], 16, 0, 0);
            __builtin_amdgcn_global_load_lds(
                (const __attribute__((address_space(1))) unsigned int*)(vs + (size_t)i * 8 * NHW),
                (__attribute__((address_space(3))) unsigned int*)&Vtile[0][wid * 16 + i * 8][0], 16, 0, 0);
        }
    }
    __syncthreads();

    int buf = 0;
    for (int chk = 0; chk < 9; chk++) {
        int m0 = chk * 64;
        if (chk < 8) {
            const unsigned short* ks = Kb + (size_t)(m0 + 64 + wid * 16 + srow) * NC + scol * 8;
            const unsigned short* vs = Vb + (size_t)(wid * 16 + srow) * NHW + (m0 + 64) + scol * 8;
            #pragma unroll
            for (int i = 0; i < 2; i++) {
                __builtin_amdgcn_global_load_lds(
                    (const __attribute__((address_space(1))) unsigned int*)(ks + (size_t)i * 8 * NC),
                    (__attribute__((address_space(3))) unsigned int*)&Ktile[buf ^ 1][wid * 16 + i * 8][0], 16, 0, 0);
                __builtin_amdgcn_global_load_lds(
                    (const __attribute__((address_space(1))) unsigned int*)(vs + (size_t)i * 8 * NHW),
                    (__attribute__((address_space(3))) unsigned int*)&Vtile[buf ^ 1][wid * 16 + i * 8][0], 16, 0, 0);
            }
        }

        floatx4 s[4];
        #pragma unroll
        for (int t = 0; t < 4; t++) {
            int row = t * 16 + cl;
            int sw = cl & 7;
            short8 bk0 = *reinterpret_cast<const short8*>(&Ktile[buf][row][(part ^ sw) * 8]);
            short8 bk1 = *reinterpret_cast<const short8*>(&Ktile[buf][row][((part + 4) ^ sw) * 8]);
            s[t] = __builtin_amdgcn_mfma_f32_16x16x32_bf16(aq0, bk0, zz, 0, 0, 0);
            s[t] = __builtin_amdgcn_mfma_f32_16x16x32_bf16(aq1, bk1, s[t], 0, 0, 0);
        }
        #pragma unroll
        for (int t = 0; t < 4; t++)
            #pragma unroll
            for (int j = 0; j < 4; j++) {
                float e = exp2f(s[t][j] * SCALE_L2E);
                es[j] += e;
                pbuf[wid][r0 + j][t * 16 + cl] = f2bf(e);
            }
        short8 pa0 = *reinterpret_cast<const short8*>(&pbuf[wid][cl][ko]);
        short8 pa1 = *reinterpret_cast<const short8*>(&pbuf[wid][cl][32 + ko]);
        #pragma unroll
        for (int ct = 0; ct < 4; ct++) {
            int row = ct * 16 + cl;
            int sw = cl & 7;
            short8 bv0 = *reinterpret_cast<const short8*>(&Vtile[buf][row][(part ^ sw) * 8]);
            short8 bv1 = *reinterpret_cast<const short8*>(&Vtile[buf][row][((part + 4) ^ sw) * 8]);
            oacc[ct] = __builtin_amdgcn_mfma_f32_16x16x32_bf16(pa0, bv0, oacc[ct], 0, 0, 0);
            oacc[ct] = __builtin_amdgcn_mfma_f32_16x16x32_bf16(pa1, bv1, oacc[ct], 0, 0, 0);
        }
        __syncthreads();
        buf ^= 1;
    }

    #pragma unroll
    for (int off = 1; off < 16; off <<= 1)
        #pragma unroll
        for (int j = 0; j < 4; j++) es[j] += __shfl_xor(es[j], off);
    float ri[4];
    #pragma unroll
    for (int j = 0; j < 4; j++) ri[j] = 1.f / es[j];

    const float* o2b = o2 + bh * 64;
    #pragma unroll
    for (int ct = 0; ct < 4; ct++) {
        float o2v = o2b[ct * 16 + cl];
        #pragma unroll
        for (int j = 0; j < 4; j++)
            pbuf[wid][r0 + j][ct * 16 + cl] = f2bf(oacc[ct][j] * ri[j] + o2v);
    }
    short8 w0 = *reinterpret_cast<const short8*>(&pbuf[wid][cl][part * 16]);
    short8 w1 = *reinterpret_cast<const short8*>(&pbuf[wid][cl][part * 16 + 8]);
    unsigned short* dst = AO + ((size_t)b * NHW + n0 + cl) * NC + h * 64 + part * 16;
    *reinterpret_cast<short8*>(dst)     = w0;
    *reinterpret_cast<short8*>(dst + 8) = w1;
}

// ---------------------------------------------------------------- launcher

extern "C" void kernel_launch(void* const* d_in, const int* in_sizes, int n_in,
                              void* d_out, int out_size, void* d_ws, size_t ws_size,
                              hipStream_t stream) {
    const float* x    = (const float*)d_in[0];
    const float* t    = (const float*)d_in[1];
    const float* Wk   = (const float*)d_in[2];
    const float* Wq   = (const float*)d_in[3];
    const float* Wt_w = (const float*)d_in[4];
    const float* Wt_b = (const float*)d_in[5];
    const float* Wm   = (const float*)d_in[6];
    const float* Wv   = (const float*)d_in[7];
    const float* Wr_w = (const float*)d_in[8];
    const float* Wr_b = (const float*)d_in[9];
    float* out = (float*)d_out;
    char* ws = (char*)d_ws;

    unsigned short* xT      = (unsigned short*)(ws);
    unsigned short* Wqkm    = (unsigned short*)(ws + 9437184);
    unsigned short* Wv_bf   = (unsigned short*)(ws + 11010048);
    unsigned short* Wr_bf   = (unsigned short*)(ws + 11534336);
    float*          tm      = (float*)(ws + 12058624);
    float*          tmerge  = (float*)(ws + 12091392);
    unsigned short* QT      = (unsigned short*)(ws + 12124160);
    unsigned short* KT      = (unsigned short*)(ws + 21561344);
    unsigned short* WmT     = (unsigned short*)(ws + 30998528);   // 1 MB
    float*          Wvm_txt = (float*)(ws + 32047104);            // 1 MB
    unsigned short* Vv      = (unsigned short*)(ws + 40435712);
    float*          o2      = (float*)(ws + 49872896);
    unsigned short* AO      = xT;   // xT dead after k_cross_o2; alias for AO
    (void)in_sizes; (void)n_in; (void)out_size; (void)ws_size;

    k_prep_all<<<9216, 256, 0, stream>>>(Wq, Wk, Wv, Wr_w, Wm, x, Wqkm, Wv_bf, Wr_bf, WmT, xT);
    k_fold<<<32, 256, 0, stream>>>(Wv_bf, WmT, Wqkm, Wvm_txt);
    k_prep_t<<<dim3(16, 4), 256, 0, stream>>>(t, Wt_w, Wt_b, Wvm_txt, tm, tmerge);
    k_gemm_qkm<<<864, 256, 0, stream>>>(Wqkm, xT, tmerge, QT, KT, Vv);
    k_cross_o2<<<128, 256, 0, stream>>>(xT, Vv, tm, o2);
    k_attn<<<1152, 256, 0, stream>>>(QT, KT, Vv, o2, AO);
    k_gemm_final<<<288, 256, 0, stream>>>(Wr_bf, AO, Wr_b, out);
}